// Round 1
// baseline (661.744 us; speedup 1.0000x reference)
//
#include <hip/hip_runtime.h>

typedef __attribute__((ext_vector_type(8))) short short8;
typedef __attribute__((ext_vector_type(4))) float f32x4;

#define KP 200            // LDS row stride in bf16 elems (100 dwords -> 4-bank step, free 2-way)
#define WS_W0 0
#define WS_WH 24576       // 128*192
#define WS_WOUT (24576 + 65536)
#define WS_TOTAL (24576 + 65536 + 2048)

__device__ __forceinline__ unsigned short f2bf(float f) {
    union { float f; unsigned int u; } v; v.f = f;
    unsigned int u = v.u;
    u += 0x7FFFu + ((u >> 16) & 1u);   // RNE
    return (unsigned short)(u >> 16);
}

__device__ __forceinline__ f32x4 mfma16(short8 a, short8 b, f32x4 c) {
    return __builtin_amdgcn_mfma_f32_16x16x32_bf16(a, b, c, 0, 0, 0);
}

// Convert fp32 weights -> bf16, pre-transposed ([n][k], zero-padded) into ws.
__global__ void prep_weights_kernel(const float* __restrict__ W0,
                                    const float* __restrict__ Wh,
                                    const float* __restrict__ Wout,
                                    unsigned short* __restrict__ wts) {
    int idx = blockIdx.x * 256 + threadIdx.x;
    if (idx < 24576) {                       // W0^T: [128][192], k<168 valid
        int n = idx / 192, k = idx - n * 192;
        float v = (k < 168) ? W0[k * 128 + n] : 0.0f;
        wts[idx] = f2bf(v);
    } else if (idx < WS_WOUT) {              // Wh[i]^T: [4][128][128]
        int r = idx - 24576;
        int layer = r >> 14, rem = r & 16383;
        int n = rem >> 7, k = rem & 127;
        wts[idx] = f2bf(Wh[(layer << 14) + (k << 7) + n]);
    } else if (idx < WS_TOTAL) {             // Wout^T: [16][128], n<4 valid
        int r = idx - WS_WOUT;
        int n = r >> 7, k = r & 127;
        float v = (n < 4) ? Wout[k * 4 + n] : 0.0f;
        wts[idx] = f2bf(v);
    }
}

__global__ __launch_bounds__(256, 2) void nerf_fused_kernel(
    const float* __restrict__ coords, const float* __restrict__ dirs,
    const float* __restrict__ env, const float* __restrict__ table,
    const unsigned short* __restrict__ wts, float* __restrict__ out) {

    __shared__ unsigned short xbuf[64 * KP];    // activations, 64 rows
    __shared__ unsigned short wbuf[128 * KP];   // current layer W^T

    const int t = threadIdx.x;
    const int wave = t >> 6;
    const int lane = t & 63;
    const int p = t & 63;                       // point within block
    const int P = blockIdx.x * 64 + p;

    // ---------- Phase 1: hash-grid encode (4 levels per wave-group) ----------
    {
        float cx = coords[P * 3 + 0];
        float cy = coords[P * 3 + 1];
        float cz = coords[P * 3 + 2];
        #pragma unroll
        for (int i = 0; i < 4; i++) {
            int l = wave * 4 + i;
            int res = 16 << l;
            float rf = (float)res;
            float sx = cx * rf, sy = cy * rf, sz = cz * rf;
            float fx = floorf(sx), fy = floorf(sy), fz = floorf(sz);
            float frx = sx - fx, fry = sy - fy, frz = sz - fz;
            int x0 = (int)fx; x0 = x0 < 0 ? 0 : (x0 > res - 1 ? res - 1 : x0);
            int y0 = (int)fy; y0 = y0 < 0 ? 0 : (y0 > res - 1 ? res - 1 : y0);
            int z0 = (int)fz; z0 = z0 < 0 ? 0 : (z0 > res - 1 ? res - 1 : z0);
            float wx0 = 1.0f - frx, wx1 = frx;
            float wy0 = 1.0f - fry, wy1 = fry;
            float wz0 = 1.0f - frz, wz1 = frz;
            const float* tbl = table + ((long long)l << 17);
            float v0 = 0.0f, v1 = 0.0f;
            if (l < 2) {   // dense: (res+1)^3 <= 65536 for res=16,32
                int s = res + 1;
                int base = x0 + s * (y0 + s * z0);
                #pragma unroll
                for (int c = 0; c < 8; c++) {
                    int id = base + (c & 1) + s * ((c >> 1) & 1) + s * s * ((c >> 2) & 1);
                    float w = ((c & 1) ? wx1 : wx0) * ((c & 2) ? wy1 : wy0) * ((c & 4) ? wz1 : wz0);
                    v0 += tbl[id * 2 + 0] * w;
                    v1 += tbl[id * 2 + 1] * w;
                }
            } else {       // hashed
                unsigned hx0 = (unsigned)x0;
                unsigned hx1 = (unsigned)(x0 + 1);
                unsigned hy0 = (unsigned)y0 * 2654435761u;
                unsigned hy1 = (unsigned)(y0 + 1) * 2654435761u;
                unsigned hz0 = (unsigned)z0 * 805459861u;
                unsigned hz1 = (unsigned)(z0 + 1) * 805459861u;
                #pragma unroll
                for (int c = 0; c < 8; c++) {
                    unsigned h = ((c & 1) ? hx1 : hx0) ^ ((c & 2) ? hy1 : hy0) ^ ((c & 4) ? hz1 : hz0);
                    int id = (int)(h & 65535u);
                    float w = ((c & 1) ? wx1 : wx0) * ((c & 2) ? wy1 : wy0) * ((c & 4) ? wz1 : wz0);
                    v0 += tbl[id * 2 + 0] * w;
                    v1 += tbl[id * 2 + 1] * w;
                }
            }
            xbuf[p * KP + 2 * l + 0] = f2bf(v0);
            xbuf[p * KP + 2 * l + 1] = f2bf(v1);
        }
    }

    // ---------- Phase 2: direction frequency encode (waves 0..2 = dim) ----------
    if (wave < 3) {
        int d = wave;
        float v = dirs[P * 3 + d];
        #pragma unroll
        for (int k = 0; k < 12; k++) {
            // sin(2^k * pi * v) = sin(2*pi * (2^(k-1) * v)); 2^(k-1)*v is EXACT
            float rev = v * (0.5f * (float)(1 << k));
            float r = rev - floorf(rev);
            float s = __builtin_amdgcn_sinf(r);
            float c = __builtin_amdgcn_cosf(r);
            xbuf[p * KP + 32 + d * 24 + k] = f2bf(s);
            xbuf[p * KP + 32 + d * 24 + 12 + k] = f2bf(c);
        }
    }

    // ---------- Phase 3: env copy (coalesced float4) ----------
    {
        int pr = t >> 2, q = t & 3;
        int Pr = blockIdx.x * 64 + pr;
        const float4* src = (const float4*)(env + (long long)Pr * 64 + q * 16);
        #pragma unroll
        for (int j = 0; j < 4; j++) {
            float4 vv = src[j];
            int kk = 104 + q * 16 + j * 4;
            xbuf[pr * KP + kk + 0] = f2bf(vv.x);
            xbuf[pr * KP + kk + 1] = f2bf(vv.y);
            xbuf[pr * KP + kk + 2] = f2bf(vv.z);
            xbuf[pr * KP + kk + 3] = f2bf(vv.w);
        }
    }

    // ---------- Phase 4: zero-pad k in [168,192) ----------
    {
        int kk = 168 + wave * 6;
        #pragma unroll
        for (int j = 0; j < 6; j++) xbuf[p * KP + kk + j] = 0;
    }

    // ---------- Stage W0^T into wbuf (128 rows x 192, 16B chunks) ----------
    for (int c = t; c < 3072; c += 256) {
        int n = c / 24, j = c - n * 24;
        *(uint4*)(&wbuf[n * KP + j * 8]) = *(const uint4*)(wts + WS_W0 + n * 192 + j * 8);
    }
    __syncthreads();

    const int mrow = wave * 16 + (lane & 15);
    const int quad = lane >> 4;
    f32x4 acc[8];

    // ---------- Layer 0: [64x192] @ [192x128] ----------
    #pragma unroll
    for (int nt = 0; nt < 8; nt++) acc[nt] = (f32x4){0.f, 0.f, 0.f, 0.f};
    #pragma unroll
    for (int ks = 0; ks < 6; ks++) {
        short8 a = *(const short8*)(xbuf + mrow * KP + ks * 32 + quad * 8);
        #pragma unroll
        for (int nt = 0; nt < 8; nt++) {
            short8 b = *(const short8*)(wbuf + (nt * 16 + (lane & 15)) * KP + ks * 32 + quad * 8);
            acc[nt] = mfma16(a, b, acc[nt]);
        }
    }
    #pragma unroll
    for (int nt = 0; nt < 8; nt++)
        #pragma unroll
        for (int r = 0; r < 4; r++) {
            float v = acc[nt][r]; v = v > 0.f ? v : 0.f;
            xbuf[(wave * 16 + quad * 4 + r) * KP + nt * 16 + (lane & 15)] = f2bf(v);
        }
    __syncthreads();

    // ---------- Hidden layers 1..4: [64x128] @ [128x128] ----------
    for (int L = 0; L < 4; L++) {
        for (int c = t; c < 2048; c += 256) {
            int n = c >> 4, j = c & 15;
            *(uint4*)(&wbuf[n * KP + j * 8]) =
                *(const uint4*)(wts + WS_WH + (L << 14) + (n << 7) + j * 8);
        }
        __syncthreads();
        #pragma unroll
        for (int nt = 0; nt < 8; nt++) acc[nt] = (f32x4){0.f, 0.f, 0.f, 0.f};
        #pragma unroll
        for (int ks = 0; ks < 4; ks++) {
            short8 a = *(const short8*)(xbuf + mrow * KP + ks * 32 + quad * 8);
            #pragma unroll
            for (int nt = 0; nt < 8; nt++) {
                short8 b = *(const short8*)(wbuf + (nt * 16 + (lane & 15)) * KP + ks * 32 + quad * 8);
                acc[nt] = mfma16(a, b, acc[nt]);
            }
        }
        #pragma unroll
        for (int nt = 0; nt < 8; nt++)
            #pragma unroll
            for (int r = 0; r < 4; r++) {
                float v = acc[nt][r]; v = v > 0.f ? v : 0.f;
                xbuf[(wave * 16 + quad * 4 + r) * KP + nt * 16 + (lane & 15)] = f2bf(v);
            }
        __syncthreads();
    }

    // ---------- Output layer: [64x128] @ [128x4] (N padded to 16) ----------
    {
        int n = t >> 4, j = t & 15;   // exactly 256 chunks
        *(uint4*)(&wbuf[n * KP + j * 8]) = *(const uint4*)(wts + WS_WOUT + (n << 7) + j * 8);
    }
    __syncthreads();
    f32x4 accO = (f32x4){0.f, 0.f, 0.f, 0.f};
    #pragma unroll
    for (int ks = 0; ks < 4; ks++) {
        short8 a = *(const short8*)(xbuf + mrow * KP + ks * 32 + quad * 8);
        short8 b = *(const short8*)(wbuf + (lane & 15) * KP + ks * 32 + quad * 8);
        accO = mfma16(a, b, accO);
    }
    {
        int col = lane & 15;
        if (col < 4) {
            #pragma unroll
            for (int r = 0; r < 4; r++) {
                int row = wave * 16 + quad * 4 + r;
                out[((long long)blockIdx.x * 64 + row) * 4 + col] = accO[r];
            }
        }
    }
}

extern "C" void kernel_launch(void* const* d_in, const int* in_sizes, int n_in,
                              void* d_out, int out_size, void* d_ws, size_t ws_size,
                              hipStream_t stream) {
    const float* coords = (const float*)d_in[0];
    const float* dirs   = (const float*)d_in[1];
    const float* env    = (const float*)d_in[2];
    const float* table  = (const float*)d_in[3];
    const float* W0     = (const float*)d_in[4];
    const float* Wh     = (const float*)d_in[5];
    const float* Wout   = (const float*)d_in[6];
    float* outp = (float*)d_out;
    unsigned short* wts = (unsigned short*)d_ws;

    // 92160 bf16 weight elems -> 360 blocks x 256
    prep_weights_kernel<<<360, 256, 0, stream>>>(W0, Wh, Wout, wts);

    const int N = 524288;
    nerf_fused_kernel<<<N / 64, 256, 0, stream>>>(coords, dirs, env, table, wts, outp);
}

// Round 2
// 603.080 us; speedup vs baseline: 1.0973x; 1.0973x over previous
//
#include <hip/hip_runtime.h>

typedef __attribute__((ext_vector_type(8))) short short8;
typedef __attribute__((ext_vector_type(4))) float f32x4;

#define N_PTS 524288

// ws layout (bytes):
//  [0, 4MB)        table packed bf16x2 per entry (uint), idx = l*65536 + i
//  [4MB, +184KB)   weights (ushort), swizzled chunk layouts:
//      p0   @ elem 0      : W0^T panel0 [128 rows][16 chunks]  (k' 0..127)
//      p1   @ elem 16384  : W0^T panel1 [128 rows][8 chunks]   (k' 128..191 = env)
//      hid  @ elem 24576  : Wh^T[4]     [128 rows][16 chunks]
//      wout @ elem 90112  : Wout^T      [16 rows][16 chunks]
//  [RESV, ...)     enc rows: 128 ushort (256B) per point of current chunk
#define WS_WTS (4 * 1024 * 1024)
#define RESV   (4 * 1024 * 1024 + 256 * 1024)

__device__ __forceinline__ unsigned short f2bf(float f) {
    union { float f; unsigned int u; } v; v.f = f;
    unsigned int u = v.u;
    u += 0x7FFFu + ((u >> 16) & 1u);   // RNE
    return (unsigned short)(u >> 16);
}
__device__ __forceinline__ float bf2f(unsigned int u) {
    union { unsigned int u; float f; } v; v.u = u << 16;
    return v.f;
}

__device__ __forceinline__ f32x4 mfma16(short8 a, short8 b, f32x4 c) {
    return __builtin_amdgcn_mfma_f32_16x16x32_bf16(a, b, c, 0, 0, 0);
}

typedef const __attribute__((address_space(1))) unsigned int ga_u32;
typedef __attribute__((address_space(3))) unsigned int ls_u32;
__device__ __forceinline__ void gl2lds16(const void* g, void* l) {
    __builtin_amdgcn_global_load_lds((ga_u32*)g, (ls_u32*)l, 16, 0, 0);
}

// ---------------- prep: table fp32 -> packed bf16x2 ----------------
__global__ void prep_table_kernel(const float* __restrict__ table,
                                  unsigned int* __restrict__ tbl) {
    int e = blockIdx.x * 256 + threadIdx.x;       // < 16*65536 = 1048576
    float2 f = ((const float2*)table)[e];
    tbl[e] = (unsigned int)f2bf(f.x) | ((unsigned int)f2bf(f.y) << 16);
}

// ---------------- prep: weights -> bf16, transposed + XOR-swizzled ----------------
// Layer-0 k-order: [0,104) = spatial+dir (enc), [104,128) = zero, [128,192) = env.
__global__ void prep_weights_kernel(const float* __restrict__ W0,
                                    const float* __restrict__ Wh,
                                    const float* __restrict__ Wout,
                                    unsigned short* __restrict__ wts) {
    int e = blockIdx.x * 256 + threadIdx.x;
    float v;
    if (e < 16384) {                               // panel0
        int n = e >> 7, w = e & 127, c = w >> 3, j = w & 7;
        int k = ((c ^ (n & 15)) << 3) + j;
        v = (k < 104) ? W0[k * 128 + n] : 0.0f;
    } else if (e < 24576) {                        // panel1 (env part of W0)
        int r = e - 16384;
        int n = r >> 6, w = r & 63, c = w >> 3, j = w & 7;
        int kk = ((c ^ (n & 7)) << 3) + j;         // 0..63
        v = W0[(104 + kk) * 128 + n];
    } else if (e < 90112) {                        // hidden
        int r = e - 24576;
        int L = r >> 14, q = r & 16383;
        int n = q >> 7, w = q & 127, c = w >> 3, j = w & 7;
        int k = ((c ^ (n & 15)) << 3) + j;
        v = Wh[(L << 14) + (k << 7) + n];
    } else if (e < 92160) {                        // wout (16 rows, n<4 valid)
        int r = e - 90112;
        int n = r >> 7, w = r & 127, c = w >> 3, j = w & 7;
        int k = ((c ^ (n & 15)) << 3) + j;
        v = (n < 4) ? Wout[(k << 2) + n] : 0.0f;
    } else return;
    wts[e] = f2bf(v);
}

// ---------------- encode: hash grid + freq -> bf16 rows [chunk][128] ----------------
__global__ __launch_bounds__(256, 4) void encode_kernel(
    const float* __restrict__ coords, const float* __restrict__ dirs,
    const unsigned int* __restrict__ tbl, unsigned int* __restrict__ enc, int base) {
    int li = blockIdx.x * 256 + threadIdx.x;
    long long p = (long long)base + li;
    float cx = coords[p * 3 + 0], cy = coords[p * 3 + 1], cz = coords[p * 3 + 2];
    unsigned int* row = enc + (size_t)li * 64;

    // dense levels 0,1
    #pragma unroll
    for (int l = 0; l < 2; l++) {
        int res = 16 << l, s = res + 1;
        float rf = (float)res;
        float sx = cx * rf, sy = cy * rf, sz = cz * rf;
        float fx = floorf(sx), fy = floorf(sy), fz = floorf(sz);
        float frx = sx - fx, fry = sy - fy, frz = sz - fz;
        int x0 = (int)fx; x0 = x0 < 0 ? 0 : (x0 > res - 1 ? res - 1 : x0);
        int y0 = (int)fy; y0 = y0 < 0 ? 0 : (y0 > res - 1 ? res - 1 : y0);
        int z0 = (int)fz; z0 = z0 < 0 ? 0 : (z0 > res - 1 ? res - 1 : z0);
        int id = x0 + s * (y0 + s * z0);
        const unsigned int* t0 = tbl + (l << 16);
        float v0 = 0.f, v1 = 0.f;
        #pragma unroll
        for (int c = 0; c < 8; c++) {
            int idc = id + (c & 1) + s * ((c >> 1) & 1) + s * s * ((c >> 2) & 1);
            unsigned int d = t0[idc];
            float w = ((c & 1) ? frx : 1.f - frx) * ((c & 2) ? fry : 1.f - fry) *
                      ((c & 4) ? frz : 1.f - frz);
            v0 += bf2f(d & 0xffffu) * w;
            v1 += bf2f(d >> 16) * w;
        }
        row[l] = (unsigned int)f2bf(v0) | ((unsigned int)f2bf(v1) << 16);
    }
    // hashed levels 2..15
    #pragma unroll 4
    for (int l = 2; l < 16; l++) {
        int res = 16 << l;
        float rf = (float)res;
        float sx = cx * rf, sy = cy * rf, sz = cz * rf;
        float fx = floorf(sx), fy = floorf(sy), fz = floorf(sz);
        float frx = sx - fx, fry = sy - fy, frz = sz - fz;
        int x0 = (int)fx; x0 = x0 < 0 ? 0 : (x0 > res - 1 ? res - 1 : x0);
        int y0 = (int)fy; y0 = y0 < 0 ? 0 : (y0 > res - 1 ? res - 1 : y0);
        int z0 = (int)fz; z0 = z0 < 0 ? 0 : (z0 > res - 1 ? res - 1 : z0);
        unsigned hx0 = (unsigned)x0, hx1 = (unsigned)(x0 + 1);
        unsigned hy0 = (unsigned)y0 * 2654435761u, hy1 = (unsigned)(y0 + 1) * 2654435761u;
        unsigned hz0 = (unsigned)z0 * 805459861u,  hz1 = (unsigned)(z0 + 1) * 805459861u;
        const unsigned int* t0 = tbl + (l << 16);
        float v0 = 0.f, v1 = 0.f;
        #pragma unroll
        for (int c = 0; c < 8; c++) {
            unsigned h = ((c & 1) ? hx1 : hx0) ^ ((c & 2) ? hy1 : hy0) ^ ((c & 4) ? hz1 : hz0);
            unsigned int d = t0[h & 65535u];
            float w = ((c & 1) ? frx : 1.f - frx) * ((c & 2) ? fry : 1.f - fry) *
                      ((c & 4) ? frz : 1.f - frz);
            v0 += bf2f(d & 0xffffu) * w;
            v1 += bf2f(d >> 16) * w;
        }
        row[l] = (unsigned int)f2bf(v0) | ((unsigned int)f2bf(v1) << 16);
    }
    // direction freq encode: k 32..103 -> dwords 16..51
    #pragma unroll
    for (int d = 0; d < 3; d++) {
        float v = dirs[p * 3 + d];
        #pragma unroll
        for (int k2 = 0; k2 < 6; k2++) {
            float r0 = v * (0.5f * (float)(1 << (2 * k2)));
            float r1 = v * (0.5f * (float)(1 << (2 * k2 + 1)));
            r0 -= floorf(r0); r1 -= floorf(r1);
            float s0 = __builtin_amdgcn_sinf(r0), s1 = __builtin_amdgcn_sinf(r1);
            float c0 = __builtin_amdgcn_cosf(r0), c1 = __builtin_amdgcn_cosf(r1);
            row[16 + d * 12 + k2]     = (unsigned int)f2bf(s0) | ((unsigned int)f2bf(s1) << 16);
            row[22 + d * 12 + k2]     = (unsigned int)f2bf(c0) | ((unsigned int)f2bf(c1) << 16);
        }
    }
    // zero pad k 104..127 -> dwords 52..63 (full line coverage, avoids RMW)
    uint4 z = {0u, 0u, 0u, 0u};
    *(uint4*)(row + 52) = z; *(uint4*)(row + 56) = z; *(uint4*)(row + 60) = z;
}

// ---------------- fused MLP: 6-layer GEMM chain ----------------
__global__ __launch_bounds__(256, 3) void mlp_kernel(
    const float* __restrict__ env, const unsigned short* __restrict__ enc,
    const unsigned short* __restrict__ wts, float* __restrict__ out, int base) {

    __shared__ __align__(16) unsigned short xbuf[64 * 136];   // activations, stride 136
    __shared__ __align__(16) unsigned short wbuf[128 * 128];  // swizzled weight chunks

    const int t = threadIdx.x;
    const int wave = t >> 6, lane = t & 63;
    const int colL = lane & 15, quad = lane >> 4;
    const int mrow = wave * 16 + colL;                 // A row within block
    const int Pl = blockIdx.x * 64 + mrow;             // local (chunk) point index
    const long long Pg = (long long)base + Pl;         // global point index

    // ---- stage W0 panel0 (2048 chunks) ----
    #pragma unroll
    for (int i = 0; i < 8; i++)
        gl2lds16(wts + (i * 256 + t) * 8, (char*)wbuf + (i * 256 + wave * 64) * 16);

    // ---- issue layer-0 A loads (registers, overlap with staging) ----
    short8 aEnc[4];
    #pragma unroll
    for (int ks = 0; ks < 4; ks++)
        aEnc[ks] = *(const short8*)(enc + (size_t)Pl * 128 + ks * 32 + quad * 8);
    float4 aEnvF[4];
    #pragma unroll
    for (int s = 0; s < 2; s++) {
        aEnvF[2 * s]     = *(const float4*)(env + Pg * 64 + s * 32 + quad * 8);
        aEnvF[2 * s + 1] = *(const float4*)(env + Pg * 64 + s * 32 + quad * 8 + 4);
    }
    __syncthreads();

    f32x4 acc[8];
    #pragma unroll
    for (int nt = 0; nt < 8; nt++) acc[nt] = (f32x4){0.f, 0.f, 0.f, 0.f};

    // ---- layer 0, panel0 (k' 0..127) ----
    #pragma unroll
    for (int ks = 0; ks < 4; ks++) {
        #pragma unroll
        for (int nt = 0; nt < 8; nt++) {
            int n = nt * 16 + colL;
            short8 b = *(const short8*)(wbuf + n * 128 + (((ks * 4 + quad) ^ colL) << 3));
            acc[nt] = mfma16(aEnc[ks], b, acc[nt]);
        }
    }
    __syncthreads();
    // ---- stage W0 panel1 (1024 chunks) ----
    #pragma unroll
    for (int i = 0; i < 4; i++)
        gl2lds16(wts + 16384 + (i * 256 + t) * 8, (char*)wbuf + (i * 256 + wave * 64) * 16);
    __syncthreads();
    // ---- layer 0, panel1 (k' 128..191 = env) ----
    #pragma unroll
    for (int ks2 = 0; ks2 < 2; ks2++) {
        float4 e0 = aEnvF[2 * ks2], e1 = aEnvF[2 * ks2 + 1];
        short8 a;
        a[0] = (short)f2bf(e0.x); a[1] = (short)f2bf(e0.y);
        a[2] = (short)f2bf(e0.z); a[3] = (short)f2bf(e0.w);
        a[4] = (short)f2bf(e1.x); a[5] = (short)f2bf(e1.y);
        a[6] = (short)f2bf(e1.z); a[7] = (short)f2bf(e1.w);
        #pragma unroll
        for (int nt = 0; nt < 8; nt++) {
            int n = nt * 16 + colL;
            short8 b = *(const short8*)(wbuf + n * 64 + (((ks2 * 4 + quad) ^ (colL & 7)) << 3));
            acc[nt] = mfma16(a, b, acc[nt]);
        }
    }
    __syncthreads();
    // ---- epilogue layer 0 -> xbuf (each wave touches only its own 16 rows) ----
    #pragma unroll
    for (int nt = 0; nt < 8; nt++)
        #pragma unroll
        for (int r = 0; r < 4; r++) {
            float v = acc[nt][r]; v = v > 0.f ? v : 0.f;
            xbuf[(wave * 16 + quad * 4 + r) * 136 + nt * 16 + colL] = f2bf(v);
        }

    // ---- hidden layers ----
    for (int L = 0; L < 4; L++) {
        #pragma unroll
        for (int i = 0; i < 8; i++)
            gl2lds16(wts + 24576 + (L << 14) + (i * 256 + t) * 8,
                     (char*)wbuf + (i * 256 + wave * 64) * 16);
        __syncthreads();
        #pragma unroll
        for (int nt = 0; nt < 8; nt++) acc[nt] = (f32x4){0.f, 0.f, 0.f, 0.f};
        #pragma unroll
        for (int ks = 0; ks < 4; ks++) {
            short8 a = *(const short8*)(xbuf + mrow * 136 + ks * 32 + quad * 8);
            #pragma unroll
            for (int nt = 0; nt < 8; nt++) {
                int n = nt * 16 + colL;
                short8 b = *(const short8*)(wbuf + n * 128 + (((ks * 4 + quad) ^ colL) << 3));
                acc[nt] = mfma16(a, b, acc[nt]);
            }
        }
        __syncthreads();
        #pragma unroll
        for (int nt = 0; nt < 8; nt++)
            #pragma unroll
            for (int r = 0; r < 4; r++) {
                float v = acc[nt][r]; v = v > 0.f ? v : 0.f;
                xbuf[(wave * 16 + quad * 4 + r) * 136 + nt * 16 + colL] = f2bf(v);
            }
    }

    // ---- output layer ----
    gl2lds16(wts + 90112 + t * 8, (char*)wbuf + (wave * 64) * 16);  // 256 chunks
    __syncthreads();
    f32x4 accO = (f32x4){0.f, 0.f, 0.f, 0.f};
    #pragma unroll
    for (int ks = 0; ks < 4; ks++) {
        short8 a = *(const short8*)(xbuf + mrow * 136 + ks * 32 + quad * 8);
        short8 b = *(const short8*)(wbuf + colL * 128 + (((ks * 4 + quad) ^ colL) << 3));
        accO = mfma16(a, b, accO);
    }
    if (colL < 4) {
        #pragma unroll
        for (int r = 0; r < 4; r++) {
            long long rowG = (long long)base + blockIdx.x * 64 + wave * 16 + quad * 4 + r;
            out[rowG * 4 + colL] = accO[r];
        }
    }
}

extern "C" void kernel_launch(void* const* d_in, const int* in_sizes, int n_in,
                              void* d_out, int out_size, void* d_ws, size_t ws_size,
                              hipStream_t stream) {
    const float* coords = (const float*)d_in[0];
    const float* dirs   = (const float*)d_in[1];
    const float* env    = (const float*)d_in[2];
    const float* table  = (const float*)d_in[3];
    const float* W0     = (const float*)d_in[4];
    const float* Wh     = (const float*)d_in[5];
    const float* Wout   = (const float*)d_in[6];
    float* outp = (float*)d_out;

    unsigned int*   tbl  = (unsigned int*)d_ws;
    unsigned short* wts  = (unsigned short*)((char*)d_ws + WS_WTS);
    unsigned short* encb = (unsigned short*)((char*)d_ws + RESV);

    prep_table_kernel<<<4096, 256, 0, stream>>>(table, tbl);
    prep_weights_kernel<<<360, 256, 0, stream>>>(W0, Wh, Wout, wts);

    // chunk points so enc region fits in ws
    long long avail = (ws_size > (size_t)RESV) ? (long long)(ws_size - RESV) : 0;
    long long maxp = avail / 256;
    int chunk = N_PTS;
    if (maxp < N_PTS) {
        chunk = (int)((maxp / 16384) * 16384);
        if (chunk <= 0) chunk = 16384;   // ws too small; best effort
    }
    for (int s0 = 0; s0 < N_PTS; s0 += chunk) {
        int n = (N_PTS - s0 < chunk) ? (N_PTS - s0) : chunk;
        encode_kernel<<<n / 256, 256, 0, stream>>>(coords, dirs, tbl, (unsigned int*)encb, s0);
        mlp_kernel<<<n / 64, 256, 0, stream>>>(env, encb, wts, outp, s0);
    }
}